// Round 3
// baseline (267.190 us; speedup 1.0000x reference)
//
#include <hip/hip_runtime.h>
#include <hip/hip_fp16.h>
#include <stdint.h>

// ---------------------------------------------------------------------------
// ClusterPolicyNetwork: MHA (fp32) + pairwise task/node MLP (f16 MFMA)
// d_out (fp32): matching_scores[1024*1024] | coord_logits[32] | attn_w[1024*1024]
// 6 launches: proj_fused -> scores -> attn_fused -> outproj -> n1h+coord -> score
// ---------------------------------------------------------------------------

typedef __attribute__((ext_vector_type(4))) float floatx4;
typedef __attribute__((ext_vector_type(8))) _Float16 half8;

// workspace offsets (bytes)
#define OFF_QKV  0x000000u   // 1024*384*4
#define OFF_CTX  0x180000u   // 1024*128*4
#define OFF_ATT  0x200000u   // 1024*128*4
#define OFF_T1H  0x280000u   // 1024*256*2 (f16, includes +b1)
#define OFF_N1H  0x300000u   // 1024*256*2 (f16)
#define OFF_W2F  0x380000u   // 65536 (f16 MFMA frags)
#define OFF_GS   0x398000u   // 128*4
#define OFF_SC   0x400000u   // 4*1024*1024*4 raw scores

__device__ __forceinline__ unsigned pkadd(unsigned a, unsigned b) {
    unsigned r; asm("v_pk_add_f16 %0, %1, %2" : "=v"(r) : "v"(a), "v"(b)); return r;
}
__device__ __forceinline__ unsigned pkmax(unsigned a, unsigned b) {
    unsigned r; asm("v_pk_max_f16 %0, %1, %2" : "=v"(r) : "v"(a), "v"(b)); return r;
}
__device__ __forceinline__ unsigned pk2h(float a, float b) {
    return (unsigned)__half_as_ushort(__float2half(a)) |
           ((unsigned)__half_as_ushort(__float2half(b)) << 16);
}

// ---------------------------------------------------------------------------
// Generic fp32 GEMM tile body (device fn): C = scale*(A @ B^T) [+ bias]
// ---------------------------------------------------------------------------
template<bool BIAS, bool F16OUT, bool COLSUM>
__device__ __forceinline__ void gemm_dev(
    const float* __restrict__ A, int lda,
    const float* __restrict__ B, int ldb,
    const float* __restrict__ bias,
    void* __restrict__ Cv, int ldc, int K, float scale,
    float* __restrict__ gsum, int m0, int n0,
    float (*As)[64], float (*Bs)[64], float* cs)
{
    const int tid = threadIdx.x;
    const int tx = tid & 15, ty = tid >> 4;
    const int lr = tid >> 2;
    const int lk = (tid & 3) * 4;
    if (COLSUM && tid < 64) cs[tid] = 0.f;
    float c[4][4] = {};

    for (int k0 = 0; k0 < K; k0 += 16) {
        float4 a  = *(const float4*)&A[(long)(m0 + lr) * lda + k0 + lk];
        float4 bb = *(const float4*)&B[(long)(n0 + lr) * ldb + k0 + lk];
        __syncthreads();
        As[lk + 0][lr] = a.x;  As[lk + 1][lr] = a.y;  As[lk + 2][lr] = a.z;  As[lk + 3][lr] = a.w;
        Bs[lk + 0][lr] = bb.x; Bs[lk + 1][lr] = bb.y; Bs[lk + 2][lr] = bb.z; Bs[lk + 3][lr] = bb.w;
        __syncthreads();
#pragma unroll
        for (int k = 0; k < 16; k++) {
            float4 av = *(const float4*)&As[k][ty * 4];
            float4 bv = *(const float4*)&Bs[k][tx * 4];
            c[0][0] += av.x * bv.x; c[0][1] += av.x * bv.y; c[0][2] += av.x * bv.z; c[0][3] += av.x * bv.w;
            c[1][0] += av.y * bv.x; c[1][1] += av.y * bv.y; c[1][2] += av.y * bv.z; c[1][3] += av.y * bv.w;
            c[2][0] += av.z * bv.x; c[2][1] += av.z * bv.y; c[2][2] += av.z * bv.z; c[2][3] += av.z * bv.w;
            c[3][0] += av.w * bv.x; c[3][1] += av.w * bv.y; c[3][2] += av.w * bv.z; c[3][3] += av.w * bv.w;
        }
    }

    float bsv[4] = {0.f, 0.f, 0.f, 0.f};
    if (BIAS) {
        float4 t = *(const float4*)&bias[n0 + tx * 4];
        bsv[0] = t.x; bsv[1] = t.y; bsv[2] = t.z; bsv[3] = t.w;
    }
#pragma unroll
    for (int i = 0; i < 4; i++) {
        float v0 = c[i][0] * scale + bsv[0];
        float v1 = c[i][1] * scale + bsv[1];
        float v2 = c[i][2] * scale + bsv[2];
        float v3 = c[i][3] * scale + bsv[3];
        long m = m0 + ty * 4 + i;
        if (F16OUT) {
            unsigned short* Cp = (unsigned short*)Cv;
            ushort4 o;
            o.x = __half_as_ushort(__float2half(v0));
            o.y = __half_as_ushort(__float2half(v1));
            o.z = __half_as_ushort(__float2half(v2));
            o.w = __half_as_ushort(__float2half(v3));
            *(ushort4*)&Cp[m * ldc + n0 + tx * 4] = o;
        } else {
            float* Cp = (float*)Cv;
            *(float4*)&Cp[m * ldc + n0 + tx * 4] = make_float4(v0, v1, v2, v3);
        }
        if (COLSUM) {
            atomicAdd(&cs[tx * 4 + 0], v0);
            atomicAdd(&cs[tx * 4 + 1], v1);
            atomicAdd(&cs[tx * 4 + 2], v2);
            atomicAdd(&cs[tx * 4 + 3], v3);
        }
    }
    if (COLSUM) {
        __syncthreads();
        if (tid < 64) atomicAdd(&gsum[n0 + tid], cs[tid]);
    }
}

// ---------------------------------------------------------------------------
// Launch 1: qkv gemm (96 blk) + t1h gemm (64 blk) + w2prep (16 blk)
// ---------------------------------------------------------------------------
__launch_bounds__(256)
__global__ void proj_fused(const float* __restrict__ node, const float* __restrict__ ipw,
                           const float* __restrict__ ipb,
                           const float* __restrict__ task, const float* __restrict__ W1,
                           const float* __restrict__ b1, const float* __restrict__ W2,
                           float* __restrict__ qkv, unsigned short* __restrict__ t1h,
                           unsigned short* __restrict__ w2f)
{
    __shared__ float As[16][64], Bs[16][64], cs[64];
    const int bid = blockIdx.x;
    if (bid < 96) {
        gemm_dev<true, false, false>(node, 128, ipw, 128, ipb, qkv, 384, 128, 1.0f,
                                     nullptr, (bid & 15) * 64, (bid >> 4) * 64, As, Bs, cs);
    } else if (bid < 160) {
        const int b = bid - 96;
        gemm_dev<true, true, false>(task, 128, W1, 256, b1, t1h, 256, 128, 1.0f,
                                    nullptr, (b & 15) * 64, (b >> 4) * 64, As, Bs, cs);
    } else {
        // W2 -> f16 MFMA fragment layout:
        // frag[((cc*8+ot)*64+lane)*8+j] = f16(W2[ot*16+(lane&15)][cc*32+(lane>>4)*8+j])
        const int gtid = (bid - 160) * 256 + threadIdx.x;  // 0..4095
        const int lane = gtid & 63, frag = gtid >> 6;
        const int cc = frag >> 3, ot = frag & 7;
        const float* src = &W2[(ot * 16 + (lane & 15)) * 256 + cc * 32 + (lane >> 4) * 8];
        uint4 o;
        o.x = pk2h(src[0], src[1]);
        o.y = pk2h(src[2], src[3]);
        o.z = pk2h(src[4], src[5]);
        o.w = pk2h(src[6], src[7]);
        ((uint4*)w2f)[gtid] = o;
    }
}

// ---------------------------------------------------------------------------
// Launch 2: scores[h] = Qh @ Kh^T / sqrt(32), grid (16,16,4)
// ---------------------------------------------------------------------------
__launch_bounds__(256)
__global__ void scores_kernel(const float* __restrict__ qkv, float* __restrict__ sc)
{
    __shared__ float As[16][64], Bs[16][64], cs[64];
    const int h = blockIdx.z;
    gemm_dev<false, false, false>(qkv + h * 32, 384, qkv + 128 + h * 32, 384, nullptr,
                                  sc + (long)h * 1048576, 1024, 32, 0.17677669529663687f,
                                  nullptr, blockIdx.x * 64, blockIdx.y * 64, As, Bs, cs);
}

// ---------------------------------------------------------------------------
// Launch 3: fused softmax stats + attn_w output + ctx. 256 blocks x 4 q-rows.
// ---------------------------------------------------------------------------
__launch_bounds__(256)
__global__ void attn_fused(const float* __restrict__ sc, const float* __restrict__ qkv,
                           float* __restrict__ attn_out, float* __restrict__ ctx)
{
    __shared__ float P[4096];          // 16 KB: 4 rows x 1024 probs
    __shared__ float sm4[4], sl4[4];
    __shared__ float ctmp[4][32][2];
    const int t = threadIdx.x;
    const int q0 = blockIdx.x * 4;
    float attnacc[16] = {};

    for (int h = 0; h < 4; h++) {
        const float* src = sc + (long)h * 1048576 + (long)q0 * 1024;
        // 1. stage S rows -> LDS (coalesced)
#pragma unroll
        for (int i = 0; i < 4; i++)
            *(float4*)&P[i * 1024 + t * 4] = *(const float4*)&src[i * 1024 + t * 4];
        __syncthreads();
        // 2. row stats: row = t>>6 (one full wave per row)
        {
            const int row = t >> 6, ln = t & 63;
            float4 vv[4];
            float mx = -1e30f;
#pragma unroll
            for (int c = 0; c < 4; c++) {
                vv[c] = *(const float4*)&P[row * 1024 + c * 256 + ln * 4];
                mx = fmaxf(mx, fmaxf(fmaxf(vv[c].x, vv[c].y), fmaxf(vv[c].z, vv[c].w)));
            }
#pragma unroll
            for (int m = 1; m < 64; m <<= 1) mx = fmaxf(mx, __shfl_xor(mx, m));
            float s = 0.f;
#pragma unroll
            for (int c = 0; c < 4; c++)
                s += __expf(vv[c].x - mx) + __expf(vv[c].y - mx) +
                     __expf(vv[c].z - mx) + __expf(vv[c].w - mx);
#pragma unroll
            for (int m = 1; m < 64; m <<= 1) s += __shfl_xor(s, m);
            if (ln == 0) { sm4[row] = mx; sl4[row] = s; }
        }
        __syncthreads();
        // 3. normalize in place + attn average accumulate
#pragma unroll
        for (int i = 0; i < 4; i++) {
            float m = sm4[i], il = 1.0f / sl4[i];
            float4 v = *(const float4*)&P[i * 1024 + t * 4];
            float4 p;
            p.x = __expf(v.x - m) * il; p.y = __expf(v.y - m) * il;
            p.z = __expf(v.z - m) * il; p.w = __expf(v.w - m) * il;
            *(float4*)&P[i * 1024 + t * 4] = p;
            attnacc[i * 4 + 0] += 0.25f * p.x;
            attnacc[i * 4 + 1] += 0.25f * p.y;
            attnacc[i * 4 + 2] += 0.25f * p.z;
            attnacc[i * 4 + 3] += 0.25f * p.w;
        }
        __syncthreads();
        // 4. ctx: thread (q = t>>6, d = t&31, ks = (t>>5)&1), 512 k each
        {
            const int q = t >> 6, d = t & 31, ks = (t >> 5) & 1;
            const int kb = ks * 512;
            const float* vp = qkv + (long)kb * 384 + 256 + h * 32 + d;
            float val = 0.f;
            for (int k = 0; k < 512; k += 4) {
                float p0 = P[q * 1024 + kb + k + 0];
                float p1 = P[q * 1024 + kb + k + 1];
                float p2 = P[q * 1024 + kb + k + 2];
                float p3 = P[q * 1024 + kb + k + 3];
                val += p0 * vp[(long)(k + 0) * 384] + p1 * vp[(long)(k + 1) * 384]
                     + p2 * vp[(long)(k + 2) * 384] + p3 * vp[(long)(k + 3) * 384];
            }
            ctmp[q][d][ks] = val;
        }
        __syncthreads();
        if (t < 128) {
            const int q = t >> 5, d = t & 31;
            ctx[(long)(q0 + q) * 128 + h * 32 + d] = ctmp[q][d][0] + ctmp[q][d][1];
        }
        __syncthreads();
    }
    // write averaged attention
#pragma unroll
    for (int i = 0; i < 4; i++) {
        float4 o = make_float4(attnacc[i * 4], attnacc[i * 4 + 1],
                               attnacc[i * 4 + 2], attnacc[i * 4 + 3]);
        *(float4*)&attn_out[(long)(q0 + i) * 1024 + t * 4] = o;
    }
}

// ---------------------------------------------------------------------------
// Launch 4: attended = ctx @ out_w^T + out_b, fused column sums. 32 blocks.
// ---------------------------------------------------------------------------
__launch_bounds__(256)
__global__ void outproj_kernel(const float* __restrict__ ctx, const float* __restrict__ outw,
                               const float* __restrict__ outb, float* __restrict__ att,
                               float* __restrict__ gs)
{
    __shared__ float As[16][64], Bs[16][64], cs[64];
    gemm_dev<true, false, true>(ctx, 128, outw, 128, outb, att, 128, 128, 1.0f,
                                gs, (blockIdx.x & 15) * 64, (blockIdx.x >> 4) * 64, As, Bs, cs);
}

// ---------------------------------------------------------------------------
// Launch 5: n1h gemm (64 blk) + coordination head (block 64)
// ---------------------------------------------------------------------------
__launch_bounds__(256)
__global__ void n1h_coord_kernel(const float* __restrict__ att, const float* __restrict__ W1b,
                                 unsigned short* __restrict__ n1h, const float* __restrict__ gs,
                                 const float* __restrict__ Wc1, const float* __restrict__ bc1,
                                 const float* __restrict__ Wc2, const float* __restrict__ bc2,
                                 float* __restrict__ outc)
{
    __shared__ float As[16][64], Bs[16][64], cs[64];
    __shared__ float g[128], hh[256];
    const int bid = blockIdx.x;
    if (bid < 64) {
        gemm_dev<false, true, false>(att, 128, W1b, 256, nullptr, n1h, 256, 128, 1.0f,
                                     nullptr, (bid & 15) * 64, (bid >> 4) * 64, As, Bs, cs);
    } else {
        const int t = threadIdx.x;
        if (t < 128) g[t] = gs[t] * (1.0f / 1024.0f);
        __syncthreads();
        {
            float a = bc1[t];
            const float* wr = &Wc1[t * 128];
            for (int d = 0; d < 128; d += 4) {
                float4 w = *(const float4*)&wr[d];
                a += w.x * g[d] + w.y * g[d + 1] + w.z * g[d + 2] + w.w * g[d + 3];
            }
            hh[t] = fmaxf(a, 0.f);
        }
        __syncthreads();
        if (t < 32) {
            float a = bc2[t];
            const float* wr = &Wc2[t * 256];
            for (int c = 0; c < 256; c += 4) {
                float4 w = *(const float4*)&wr[c];
                a += w.x * hh[c] + w.y * hh[c + 1] + w.z * hh[c + 2] + w.w * hh[c + 3];
            }
            outc[t] = a;
        }
    }
}

// ---------------------------------------------------------------------------
// Launch 6: matching scores. Swapped-operand MFMA: D' = W2 . h1^T so kout is
// on the (quad,reg) axis -> W3 reduction is in-lane + 2 shuffles, b2 folds
// into acc init, store uses all 64 lanes. t1h loads software-pipelined 1 cc.
// ---------------------------------------------------------------------------
__launch_bounds__(256, 2)
__global__ void score_kernel(const unsigned short* __restrict__ t1h,
                             const unsigned short* __restrict__ n1h,
                             const unsigned short* __restrict__ w2f,
                             const float* __restrict__ b2, const float* __restrict__ W3,
                             const float* __restrict__ b3, float* __restrict__ out)
{
    __shared__ unsigned short w2s[32768];   // 64 KB
    const int tid = threadIdx.x;
    const int lane = tid & 63;
    const int wv = tid >> 6;
    const int col = lane & 15;
    const int quad = lane >> 4;
    const int nb = blockIdx.x * 64 + wv * 16;
    const int tb = blockIdx.y * 32;

    // stage W2 fragments -> LDS
    {
        const uint4* src = (const uint4*)w2f;
        uint4* dst = (uint4*)w2s;
#pragma unroll
        for (int i = 0; i < 16; i++) dst[tid + i * 256] = src[tid + i * 256];
    }

    // n1 slice for this lane (16 n-rows per wave), all K=256: 32 VGPRs
    const int myn = nb + col;
    uint4 n1p[8];
#pragma unroll
    for (int cc = 0; cc < 8; cc++)
        n1p[cc] = *(const uint4*)(n1h + (long)myn * 256 + cc * 32 + quad * 8);

    const float b3s = b3[0];
    __syncthreads();

    for (int tg = 0; tg < 8; tg++) {
        // acc init = b2 (kout = ot*16 + quad*4 + reg), same for all 4 t's
        floatx4 acc[4][8];
#pragma unroll
        for (int ot = 0; ot < 8; ot++) {
            float4 bq = *(const float4*)&b2[ot * 16 + quad * 4];
            floatx4 ini; ini[0] = bq.x; ini[1] = bq.y; ini[2] = bq.z; ini[3] = bq.w;
#pragma unroll
            for (int tt = 0; tt < 4; tt++) acc[tt][ot] = ini;
        }

        // prefetch t-data for cc=0
        uint4 tcur[4];
#pragma unroll
        for (int tt = 0; tt < 4; tt++)
            tcur[tt] = *(const uint4*)(t1h + (long)(tb + tg * 4 + tt) * 256 + quad * 8);

#pragma unroll
        for (int cc = 0; cc < 8; cc++) {
            uint4 tnxt[4];
            if (cc < 7) {
#pragma unroll
                for (int tt = 0; tt < 4; tt++)
                    tnxt[tt] = *(const uint4*)(t1h + (long)(tb + tg * 4 + tt) * 256 + (cc + 1) * 32 + quad * 8);
            }
            const unsigned* npu = (const unsigned*)&n1p[cc];
            union { unsigned u[4]; half8 h; } af[4];
#pragma unroll
            for (int tt = 0; tt < 4; tt++) {
                const unsigned* tpu = (const unsigned*)&tcur[tt];
#pragma unroll
                for (int p = 0; p < 4; p++)
                    af[tt].u[p] = pkmax(pkadd(tpu[p], npu[p]), 0u);
            }
#pragma unroll
            for (int ot = 0; ot < 8; ot++) {
                union { uint4 u; half8 h; } bf;
                bf.u = *(const uint4*)&w2s[((cc * 8 + ot) * 64 + lane) * 8];
#pragma unroll
                for (int tt = 0; tt < 4; tt++)   // A = W2-frag, B = h1-frag
                    acc[tt][ot] = __builtin_amdgcn_mfma_f32_16x16x32_f16(bf.h, af[tt].h, acc[tt][ot], 0, 0, 0);
            }
            if (cc < 7) {
#pragma unroll
                for (int tt = 0; tt < 4; tt++) tcur[tt] = tnxt[tt];
            }
        }

        // epilogue: per tt, in-lane reduce over (ot,reg), 2 shuffles over quad
        float outv = 0.f;
#pragma unroll
        for (int tt = 0; tt < 4; tt++) {
            float pa = 0.f, pb = 0.f;
#pragma unroll
            for (int ot = 0; ot < 8; ot++) {
                float4 wq = *(const float4*)&W3[ot * 16 + quad * 4];
                floatx4 a = acc[tt][ot];
                pa += fmaxf(a[0], 0.f) * wq.x + fmaxf(a[2], 0.f) * wq.z;
                pb += fmaxf(a[1], 0.f) * wq.y + fmaxf(a[3], 0.f) * wq.w;
            }
            float p = pa + pb;
            p += __shfl_xor(p, 16);
            p += __shfl_xor(p, 32);
            if (quad == tt) outv = p;   // quad q stores t = tg*4 + q
        }
        out[(long)(tb + tg * 4 + quad) * 1024 + nb + col] =
            1.0f / (1.0f + __expf(-(outv + b3s)));
    }
}

// ---------------------------------------------------------------------------
extern "C" void kernel_launch(void* const* d_in, const int* in_sizes, int n_in,
                              void* d_out, int out_size, void* d_ws, size_t ws_size,
                              hipStream_t stream)
{
    const float* node = (const float*)d_in[0];
    const float* task = (const float*)d_in[1];
    const float* ipw  = (const float*)d_in[2];
    const float* ipb  = (const float*)d_in[3];
    const float* outw = (const float*)d_in[4];
    const float* outb = (const float*)d_in[5];
    const float* W1   = (const float*)d_in[6];
    const float* b1   = (const float*)d_in[7];
    const float* W2   = (const float*)d_in[8];
    const float* b2   = (const float*)d_in[9];
    const float* W3   = (const float*)d_in[10];
    const float* b3   = (const float*)d_in[11];
    const float* Wc1  = (const float*)d_in[12];
    const float* bc1  = (const float*)d_in[13];
    const float* Wc2  = (const float*)d_in[14];
    const float* bc2  = (const float*)d_in[15];

    char* ws = (char*)d_ws;
    float* qkv = (float*)(ws + OFF_QKV);
    float* sc  = (float*)(ws + OFF_SC);
    float* ctx = (float*)(ws + OFF_CTX);
    float* att = (float*)(ws + OFF_ATT);
    unsigned short* t1h = (unsigned short*)(ws + OFF_T1H);
    unsigned short* n1h = (unsigned short*)(ws + OFF_N1H);
    unsigned short* w2f = (unsigned short*)(ws + OFF_W2F);
    float* gs = (float*)(ws + OFF_GS);

    float* out_match = (float*)d_out;
    float* out_coord = out_match + 1048576;
    float* out_attn  = out_coord + 32;

    hipMemsetAsync(gs, 0, 512, stream);
    // 1. qkv + t1h + w2prep
    proj_fused<<<dim3(176, 1, 1), 256, 0, stream>>>(
        node, ipw, ipb, task, W1, b1, W2, qkv, t1h, w2f);
    // 2. scores
    scores_kernel<<<dim3(16, 16, 4), 256, 0, stream>>>(qkv, sc);
    // 3. softmax stats + attn_w + ctx
    attn_fused<<<dim3(256, 1, 1), 256, 0, stream>>>(sc, qkv, out_attn, ctx);
    // 4. out-projection + column sums
    outproj_kernel<<<dim3(32, 1, 1), 256, 0, stream>>>(ctx, outw, outb, att, gs);
    // 5. n1h + coordination head
    n1h_coord_kernel<<<dim3(65, 1, 1), 256, 0, stream>>>(
        att, W1 + 128, n1h, gs, Wc1, bc1, Wc2, bc2, out_coord);
    // 6. matching scores (68.7 GFLOP)
    score_kernel<<<dim3(16, 32, 1), 256, 0, stream>>>(t1h, n1h, w2f, b2, W3, b3, out_match);
}

// Round 4
// 235.253 us; speedup vs baseline: 1.1358x; 1.1358x over previous
//
#include <hip/hip_runtime.h>
#include <hip/hip_fp16.h>
#include <stdint.h>

// ---------------------------------------------------------------------------
// ClusterPolicyNetwork: MHA (fp32 scores, f16 probs) + pairwise MLP (f16 MFMA)
// d_out (fp32): matching_scores[1024*1024] | coord_logits[32] | attn_w[1024*1024]
// Launches: memset(gs) -> proj_fused -> scores -> attn_mega -> score(+coord)
// ---------------------------------------------------------------------------

typedef __attribute__((ext_vector_type(4))) float floatx4;
typedef __attribute__((ext_vector_type(8))) _Float16 half8;

// workspace offsets (bytes)
#define OFF_QKV  0x000000u   // 1024*384*4
#define OFF_T1H  0x280000u   // 1024*256*2 (f16, includes +b1)
#define OFF_N1H  0x300000u   // 1024*256*2 (f16)
#define OFF_W2F  0x380000u   // 65536 (f16 MFMA frags)
#define OFF_GS   0x398000u   // 128*4
#define OFF_SC   0x400000u   // 4*1024*1024*4 raw scores

__device__ __forceinline__ unsigned pkadd(unsigned a, unsigned b) {
    unsigned r; asm("v_pk_add_f16 %0, %1, %2" : "=v"(r) : "v"(a), "v"(b)); return r;
}
__device__ __forceinline__ unsigned pkmax(unsigned a, unsigned b) {
    unsigned r; asm("v_pk_max_f16 %0, %1, %2" : "=v"(r) : "v"(a), "v"(b)); return r;
}
__device__ __forceinline__ unsigned pk2h(float a, float b) {
    return (unsigned)__half_as_ushort(__float2half(a)) |
           ((unsigned)__half_as_ushort(__float2half(b)) << 16);
}

// ---------------------------------------------------------------------------
// fp32 GEMM tile body: C = scale*(A @ B^T) [+ bias], 64x64 tile, 256 thr.
// ---------------------------------------------------------------------------
template<bool BIAS, bool F16OUT>
__device__ __forceinline__ void gemm_dev(
    const float* __restrict__ A, int lda,
    const float* __restrict__ B, int ldb,
    const float* __restrict__ bias,
    void* __restrict__ Cv, int ldc, int K, float scale,
    int m0, int n0, float (*As)[64], float (*Bs)[64])
{
    const int tid = threadIdx.x;
    const int tx = tid & 15, ty = tid >> 4;
    const int lr = tid >> 2;
    const int lk = (tid & 3) * 4;
    float c[4][4] = {};

    for (int k0 = 0; k0 < K; k0 += 16) {
        float4 a  = *(const float4*)&A[(long)(m0 + lr) * lda + k0 + lk];
        float4 bb = *(const float4*)&B[(long)(n0 + lr) * ldb + k0 + lk];
        __syncthreads();
        As[lk + 0][lr] = a.x;  As[lk + 1][lr] = a.y;  As[lk + 2][lr] = a.z;  As[lk + 3][lr] = a.w;
        Bs[lk + 0][lr] = bb.x; Bs[lk + 1][lr] = bb.y; Bs[lk + 2][lr] = bb.z; Bs[lk + 3][lr] = bb.w;
        __syncthreads();
#pragma unroll
        for (int k = 0; k < 16; k++) {
            float4 av = *(const float4*)&As[k][ty * 4];
            float4 bv = *(const float4*)&Bs[k][tx * 4];
            c[0][0] += av.x * bv.x; c[0][1] += av.x * bv.y; c[0][2] += av.x * bv.z; c[0][3] += av.x * bv.w;
            c[1][0] += av.y * bv.x; c[1][1] += av.y * bv.y; c[1][2] += av.y * bv.z; c[1][3] += av.y * bv.w;
            c[2][0] += av.z * bv.x; c[2][1] += av.z * bv.y; c[2][2] += av.z * bv.z; c[2][3] += av.z * bv.w;
            c[3][0] += av.w * bv.x; c[3][1] += av.w * bv.y; c[3][2] += av.w * bv.z; c[3][3] += av.w * bv.w;
        }
    }

    float bsv[4] = {0.f, 0.f, 0.f, 0.f};
    if (BIAS) {
        float4 t = *(const float4*)&bias[n0 + tx * 4];
        bsv[0] = t.x; bsv[1] = t.y; bsv[2] = t.z; bsv[3] = t.w;
    }
#pragma unroll
    for (int i = 0; i < 4; i++) {
        float v0 = c[i][0] * scale + bsv[0];
        float v1 = c[i][1] * scale + bsv[1];
        float v2 = c[i][2] * scale + bsv[2];
        float v3 = c[i][3] * scale + bsv[3];
        long m = m0 + ty * 4 + i;
        if (F16OUT) {
            unsigned short* Cp = (unsigned short*)Cv;
            ushort4 o;
            o.x = __half_as_ushort(__float2half(v0));
            o.y = __half_as_ushort(__float2half(v1));
            o.z = __half_as_ushort(__float2half(v2));
            o.w = __half_as_ushort(__float2half(v3));
            *(ushort4*)&Cp[m * ldc + n0 + tx * 4] = o;
        } else {
            float* Cp = (float*)Cv;
            *(float4*)&Cp[m * ldc + n0 + tx * 4] = make_float4(v0, v1, v2, v3);
        }
    }
}

// ---------------------------------------------------------------------------
// Launch 1: qkv gemm (96 blk) + t1h gemm (64 blk) + w2prep (16 blk)
// ---------------------------------------------------------------------------
__launch_bounds__(256)
__global__ void proj_fused(const float* __restrict__ node, const float* __restrict__ ipw,
                           const float* __restrict__ ipb,
                           const float* __restrict__ task, const float* __restrict__ W1,
                           const float* __restrict__ b1, const float* __restrict__ W2,
                           float* __restrict__ qkv, unsigned short* __restrict__ t1h,
                           unsigned short* __restrict__ w2f)
{
    __shared__ float As[16][64], Bs[16][64];
    const int bid = blockIdx.x;
    if (bid < 96) {
        gemm_dev<true, false>(node, 128, ipw, 128, ipb, qkv, 384, 128, 1.0f,
                              (bid & 15) * 64, (bid >> 4) * 64, As, Bs);
    } else if (bid < 160) {
        const int b = bid - 96;
        gemm_dev<true, true>(task, 128, W1, 256, b1, t1h, 256, 128, 1.0f,
                             (b & 15) * 64, (b >> 4) * 64, As, Bs);
    } else {
        // W2 -> f16 MFMA fragment layout:
        // frag[((cc*8+ot)*64+lane)*8+j] = f16(W2[ot*16+(lane&15)][cc*32+(lane>>4)*8+j])
        const int gtid = (bid - 160) * 256 + threadIdx.x;  // 0..4095
        const int lane = gtid & 63, frag = gtid >> 6;
        const int cc = frag >> 3, ot = frag & 7;
        const float* src = &W2[(ot * 16 + (lane & 15)) * 256 + cc * 32 + (lane >> 4) * 8];
        uint4 o;
        o.x = pk2h(src[0], src[1]);
        o.y = pk2h(src[2], src[3]);
        o.z = pk2h(src[4], src[5]);
        o.w = pk2h(src[6], src[7]);
        ((uint4*)w2f)[gtid] = o;
    }
}

// ---------------------------------------------------------------------------
// Launch 2: scores[h] = Qh @ Kh^T / sqrt(32), grid (16,16,4)
// ---------------------------------------------------------------------------
__launch_bounds__(256)
__global__ void scores_kernel(const float* __restrict__ qkv, float* __restrict__ sc)
{
    __shared__ float As[16][64], Bs[16][64];
    const int h = blockIdx.z;
    gemm_dev<false, false>(qkv + h * 32, 384, qkv + 128 + h * 32, 384, nullptr,
                           sc + (long)h * 1048576, 1024, 32, 0.17677669529663687f,
                           blockIdx.x * 64, blockIdx.y * 64, As, Bs);
}

// ---------------------------------------------------------------------------
// Launch 3: attn_mega — per block 4 q-rows, 256 blocks (1/CU).
// stats + attn_w + ctx + out-proj + gs col-sums + n1h, all row-local.
// Probs held as f16 in LDS (32 KB).
// ---------------------------------------------------------------------------
__launch_bounds__(256)
__global__ void attn_mega(const float* __restrict__ sc, const float* __restrict__ qkv,
                          const float* __restrict__ outw, const float* __restrict__ outb,
                          const float* __restrict__ W1,
                          float* __restrict__ attn_out, unsigned short* __restrict__ n1h,
                          float* __restrict__ gs)
{
    __shared__ unsigned short Ps[16 * 1024];   // [h*4+q][k] f16 scores -> probs (32 KB)
    __shared__ float ctp[2][4][128];           // ctx ksplit partials
    __shared__ float attr[4][128];             // attended rows
    __shared__ float stm[16], stl[16];
    const int t = threadIdx.x;
    const int q0 = blockIdx.x * 4;

    // phase 1: stage raw scores as f16
#pragma unroll
    for (int r = 0; r < 16; r++) {
        const int h = r >> 2, q = r & 3;
        float4 v = *(const float4*)&sc[(long)h * 1048576 + (long)(q0 + q) * 1024 + t * 4];
        ushort4 o;
        o.x = __half_as_ushort(__float2half(v.x));
        o.y = __half_as_ushort(__float2half(v.y));
        o.z = __half_as_ushort(__float2half(v.z));
        o.w = __half_as_ushort(__float2half(v.w));
        *(ushort4*)&Ps[r * 1024 + t * 4] = o;
    }
    __syncthreads();

    // phase 2: row stats (wave wv = head h; full-wave reduction per q)
    {
        const int h = t >> 6, ln = t & 63;
#pragma unroll
        for (int q = 0; q < 4; q++) {
            const int base = (h * 4 + q) * 1024 + ln * 16;
            float v[16];
            float mx = -1e30f;
#pragma unroll
            for (int i = 0; i < 8; i++) {
                float2 f = __half22float2(*(const __half2*)&Ps[base + i * 2]);
                v[2 * i] = f.x; v[2 * i + 1] = f.y;
                mx = fmaxf(mx, fmaxf(f.x, f.y));
            }
#pragma unroll
            for (int m = 1; m < 64; m <<= 1) mx = fmaxf(mx, __shfl_xor(mx, m));
            float s = 0.f;
#pragma unroll
            for (int i = 0; i < 16; i++) s += __expf(v[i] - mx);
#pragma unroll
            for (int m = 1; m < 64; m <<= 1) s += __shfl_xor(s, m);
            if (ln == 0) { stm[h * 4 + q] = mx; stl[h * 4 + q] = s; }
        }
    }
    __syncthreads();

    // phase 3: normalize in place (f16) + head-averaged attn accumulation
    {
        float acc[4][4] = {};
#pragma unroll
        for (int r = 0; r < 16; r++) {
            const int q = r & 3;
            const float m = stm[r], il = 1.0f / stl[r];
            ushort4 u = *(const ushort4*)&Ps[r * 1024 + t * 4];
            float p0 = __expf(__half2float(__ushort_as_half(u.x)) - m) * il;
            float p1 = __expf(__half2float(__ushort_as_half(u.y)) - m) * il;
            float p2 = __expf(__half2float(__ushort_as_half(u.z)) - m) * il;
            float p3 = __expf(__half2float(__ushort_as_half(u.w)) - m) * il;
            ushort4 o;
            o.x = __half_as_ushort(__float2half(p0));
            o.y = __half_as_ushort(__float2half(p1));
            o.z = __half_as_ushort(__float2half(p2));
            o.w = __half_as_ushort(__float2half(p3));
            *(ushort4*)&Ps[r * 1024 + t * 4] = o;
            acc[q][0] += 0.25f * p0; acc[q][1] += 0.25f * p1;
            acc[q][2] += 0.25f * p2; acc[q][3] += 0.25f * p3;
        }
#pragma unroll
        for (int q = 0; q < 4; q++)
            *(float4*)&attn_out[(long)(q0 + q) * 1024 + t * 4] =
                make_float4(acc[q][0], acc[q][1], acc[q][2], acc[q][3]);
    }
    __syncthreads();

    // phase 4: ctx = P @ V. thread = (hd = h*32+d, ks); V reads lane-coalesced.
    {
        const int hd = t & 127, ks = t >> 7;
        const int h = hd >> 5;
        float ca[4] = {};
        const float* vp = qkv + 256 + hd;
        for (int k0 = ks * 512; k0 < ks * 512 + 512; k0 += 4) {
            float v0 = vp[(long)(k0 + 0) * 384];
            float v1 = vp[(long)(k0 + 1) * 384];
            float v2 = vp[(long)(k0 + 2) * 384];
            float v3 = vp[(long)(k0 + 3) * 384];
#pragma unroll
            for (int q = 0; q < 4; q++) {
                float2 fa = __half22float2(*(const __half2*)&Ps[(h * 4 + q) * 1024 + k0]);
                float2 fb = __half22float2(*(const __half2*)&Ps[(h * 4 + q) * 1024 + k0 + 2]);
                ca[q] += fa.x * v0 + fa.y * v1 + fb.x * v2 + fb.y * v3;
            }
        }
#pragma unroll
        for (int q = 0; q < 4; q++) ctp[ks][q][hd] = ca[q];
    }
    __syncthreads();
    // combine ksplit halves: ctp[0] += ctp[1]
    {
        float* cf = &ctp[0][0][0];
        cf[t] += cf[t + 512];
        cf[t + 256] += cf[t + 768];
    }
    __syncthreads();

    // phase 5: attended rows = ctx @ outw^T + outb (row-local)
    {
        const int j = t & 127, qp = t >> 7;
        float a0 = outb[j], a1 = a0;
        const float* wr = &outw[j * 128];
        for (int d = 0; d < 128; d += 4) {
            float4 w  = *(const float4*)&wr[d];
            float4 c0 = *(const float4*)&ctp[0][qp * 2 + 0][d];
            float4 c1 = *(const float4*)&ctp[0][qp * 2 + 1][d];
            a0 += w.x * c0.x + w.y * c0.y + w.z * c0.z + w.w * c0.w;
            a1 += w.x * c1.x + w.y * c1.y + w.z * c1.z + w.w * c1.w;
        }
        attr[qp * 2 + 0][j] = a0;
        attr[qp * 2 + 1][j] = a1;
    }
    __syncthreads();
    if (t < 128) atomicAdd(&gs[t], attr[0][t] + attr[1][t] + attr[2][t] + attr[3][t]);

    // phase 6: n1h rows = attended @ W1[:,128:]^T (f16 out, no bias)
    {
        const int c = t;
        const float* wr = &W1[c * 256 + 128];
        float n[4] = {};
        for (int d = 0; d < 128; d += 4) {
            float4 w = *(const float4*)&wr[d];
#pragma unroll
            for (int q = 0; q < 4; q++) {
                float4 a = *(const float4*)&attr[q][d];
                n[q] += w.x * a.x + w.y * a.y + w.z * a.z + w.w * a.w;
            }
        }
#pragma unroll
        for (int q = 0; q < 4; q++)
            n1h[(long)(q0 + q) * 256 + c] = __half_as_ushort(__float2half(n[q]));
    }
}

// ---------------------------------------------------------------------------
// Launch 4: matching scores (grid 16x33; row y==32 hosts the coord head).
// Swapped-operand MFMA: D' = W2 . h1^T (kout on quad/reg axis), b2 in acc
// init, in-lane W3 reduce + 2 shuffles, all-lane store. t-loads just-in-time
// (round-2 pattern: no prefetch, no spills).
// ---------------------------------------------------------------------------
__launch_bounds__(256, 2)
__global__ void score_kernel(const unsigned short* __restrict__ t1h,
                             const unsigned short* __restrict__ n1h,
                             const unsigned short* __restrict__ w2f,
                             const float* __restrict__ b2, const float* __restrict__ W3,
                             const float* __restrict__ b3, float* __restrict__ out,
                             const float* __restrict__ gs,
                             const float* __restrict__ Wc1, const float* __restrict__ bc1,
                             const float* __restrict__ Wc2, const float* __restrict__ bc2,
                             float* __restrict__ outc)
{
    __shared__ unsigned short w2s[32768];   // 64 KB
    const int tid = threadIdx.x;

    if (blockIdx.y == 32) {
        // coordination head (one block does it; LDS reused from w2s)
        if (blockIdx.x != 0) return;
        float* g  = (float*)w2s;
        float* hh = g + 128;
        if (tid < 128) g[tid] = gs[tid] * (1.0f / 1024.0f);
        __syncthreads();
        {
            float a = bc1[tid];
            const float* wr = &Wc1[tid * 128];
            for (int d = 0; d < 128; d += 4) {
                float4 w = *(const float4*)&wr[d];
                a += w.x * g[d] + w.y * g[d + 1] + w.z * g[d + 2] + w.w * g[d + 3];
            }
            hh[tid] = fmaxf(a, 0.f);
        }
        __syncthreads();
        if (tid < 32) {
            float a = bc2[tid];
            const float* wr = &Wc2[tid * 256];
            for (int c = 0; c < 256; c += 4) {
                float4 w = *(const float4*)&wr[c];
                a += w.x * hh[c] + w.y * hh[c + 1] + w.z * hh[c + 2] + w.w * hh[c + 3];
            }
            outc[tid] = a;
        }
        return;
    }

    const int lane = tid & 63;
    const int wv = tid >> 6;
    const int col = lane & 15;
    const int quad = lane >> 4;
    const int nb = blockIdx.x * 64 + wv * 16;
    const int tb = blockIdx.y * 32;

    // stage W2 fragments -> LDS
    {
        const uint4* src = (const uint4*)w2f;
        uint4* dst = (uint4*)w2s;
#pragma unroll
        for (int i = 0; i < 16; i++) dst[tid + i * 256] = src[tid + i * 256];
    }

    // n1 slice for this lane (16 n-rows per wave), all K=256: 32 VGPRs
    const int myn = nb + col;
    uint4 n1p[8];
#pragma unroll
    for (int cc = 0; cc < 8; cc++)
        n1p[cc] = *(const uint4*)(n1h + (long)myn * 256 + cc * 32 + quad * 8);

    const float b3s = b3[0];
    __syncthreads();

    for (int tg = 0; tg < 8; tg++) {
        // acc init = b2 (kout = ot*16 + quad*4 + reg), same for all 4 t's
        floatx4 acc[4][8];
#pragma unroll
        for (int ot = 0; ot < 8; ot++) {
            float4 bq = *(const float4*)&b2[ot * 16 + quad * 4];
            floatx4 ini; ini[0] = bq.x; ini[1] = bq.y; ini[2] = bq.z; ini[3] = bq.w;
#pragma unroll
            for (int tt = 0; tt < 4; tt++) acc[tt][ot] = ini;
        }

#pragma unroll
        for (int cc = 0; cc < 8; cc++) {
            // just-in-time t-loads (L1-hot, no prefetch => no spills)
            uint4 tp[4];
#pragma unroll
            for (int tt = 0; tt < 4; tt++)
                tp[tt] = *(const uint4*)(t1h + (long)(tb + tg * 4 + tt) * 256 + cc * 32 + quad * 8);

            const unsigned* npu = (const unsigned*)&n1p[cc];
            union { unsigned u[4]; half8 h; } af[4];
#pragma unroll
            for (int tt = 0; tt < 4; tt++) {
                const unsigned* tpu = (const unsigned*)&tp[tt];
#pragma unroll
                for (int p = 0; p < 4; p++)
                    af[tt].u[p] = pkmax(pkadd(tpu[p], npu[p]), 0u);
            }
#pragma unroll
            for (int ot = 0; ot < 8; ot++) {
                union { uint4 u; half8 h; } bf;
                bf.u = *(const uint4*)&w2s[((cc * 8 + ot) * 64 + lane) * 8];
#pragma unroll
                for (int tt = 0; tt < 4; tt++)   // A = W2-frag, B = h1-frag
                    acc[tt][ot] = __builtin_amdgcn_mfma_f32_16x16x32_f16(bf.h, af[tt].h, acc[tt][ot], 0, 0, 0);
            }
        }

        // epilogue: in-lane reduce over (ot,reg), 2 shuffles over quad
        float outv = 0.f;
#pragma unroll
        for (int tt = 0; tt < 4; tt++) {
            float pa = 0.f, pb = 0.f;
#pragma unroll
            for (int ot = 0; ot < 8; ot++) {
                float4 wq = *(const float4*)&W3[ot * 16 + quad * 4];
                floatx4 a = acc[tt][ot];
                pa += fmaxf(a[0], 0.f) * wq.x + fmaxf(a[2], 0.f) * wq.z;
                pb += fmaxf(a[1], 0.f) * wq.y + fmaxf(a[3], 0.f) * wq.w;
            }
            float p = pa + pb;
            p += __shfl_xor(p, 16);
            p += __shfl_xor(p, 32);
            if (quad == tt) outv = p;   // quad q keeps t = tg*4 + q
        }
        out[(long)(tb + tg * 4 + quad) * 1024 + nb + col] =
            1.0f / (1.0f + __expf(-(outv + b3s)));
    }
}

// ---------------------------------------------------------------------------
extern "C" void kernel_launch(void* const* d_in, const int* in_sizes, int n_in,
                              void* d_out, int out_size, void* d_ws, size_t ws_size,
                              hipStream_t stream)
{
    const float* node = (const float*)d_in[0];
    const float* task = (const float*)d_in[1];
    const float* ipw  = (const float*)d_in[2];
    const float* ipb  = (const float*)d_in[3];
    const float* outw = (const float*)d_in[4];
    const float* outb = (const float*)d_in[5];
    const float* W1   = (const float*)d_in[6];
    const float* b1   = (const float*)d_in[7];
    const float* W2   = (const float*)d_in[8];
    const float* b2   = (const float*)d_in[9];
    const float* W3   = (const float*)d_in[10];
    const float* b3   = (const float*)d_in[11];
    const float* Wc1  = (const float*)d_in[12];
    const float* bc1  = (const float*)d_in[13];
    const float* Wc2  = (const float*)d_in[14];
    const float* bc2  = (const float*)d_in[15];

    char* ws = (char*)d_ws;
    float* qkv = (float*)(ws + OFF_QKV);
    float* sc  = (float*)(ws + OFF_SC);
    unsigned short* t1h = (unsigned short*)(ws + OFF_T1H);
    unsigned short* n1h = (unsigned short*)(ws + OFF_N1H);
    unsigned short* w2f = (unsigned short*)(ws + OFF_W2F);
    float* gs = (float*)(ws + OFF_GS);

    float* out_match = (float*)d_out;
    float* out_coord = out_match + 1048576;
    float* out_attn  = out_coord + 32;

    hipMemsetAsync(gs, 0, 512, stream);
    // 1. qkv + t1h + w2prep
    proj_fused<<<dim3(176, 1, 1), 256, 0, stream>>>(
        node, ipw, ipb, task, W1, b1, W2, qkv, t1h, w2f);
    // 2. raw scores
    scores_kernel<<<dim3(16, 16, 4), 256, 0, stream>>>(qkv, sc);
    // 3. stats + attn_w + ctx + out-proj + gs + n1h
    attn_mega<<<dim3(256, 1, 1), 256, 0, stream>>>(
        sc, qkv, outw, outb, W1, out_attn, n1h, gs);
    // 4. matching scores + coord head
    score_kernel<<<dim3(16, 33, 1), 256, 0, stream>>>(
        t1h, n1h, w2f, b2, W3, b3, out_match,
        gs, Wc1, bc1, Wc2, bc2, out_coord);
}